// Round 4
// baseline (507.450 us; speedup 1.0000x reference)
//
#include <hip/hip_runtime.h>
#include <hip/hip_cooperative_groups.h>
#include <math.h>

namespace cg = cooperative_groups;

#define F 64
#define REG_C 0.01f
#define INV_LN2 1.4426950408889634f

// ws float layout (no zero-init required; every slot fully overwritten):
//   wsA: [2F][G]  transposed stage-A partials: wsA[f*G + p] = block p's
//                 partial of element f (rows 0..63 = sI, 64..127 = sJ).
//                 Transposed so phase-B's cross-block reduce is per-thread
//                 CONTIGUOUS float4 reads.
//   wsB: [2G]     per-block scalars: [p]=sum I^2, [G+p]=sum J^2
//   wsC: [2G]     per-block scalars: [p]=sum U^2, [G+p]=sum log_sigmoid

template<int RPB>
__global__ __launch_bounds__(256, 1) void k_fused(
    const float* __restrict__ embed_user,
    const float* __restrict__ embed_item,
    const int* __restrict__ uu,
    const int* __restrict__ ii,
    const int* __restrict__ jj,
    float* __restrict__ wsA,
    float* __restrict__ wsB,
    float* __restrict__ wsC,
    float* __restrict__ out,
    int Bn)
{
    cg::grid_group grid = cg::this_grid();
    const int G    = gridDim.x;
    const int t    = threadIdx.x;
    const int q    = t & 15;     // float4 quad within the 64-float row
    const int rg   = t >> 4;     // row group 0..15
    const int wave = t >> 6, lane = t & 63;
    const int base = blockIdx.x * RPB;

    // ---- stage indices in LDS (coalesced; removes dependent index loads) ----
    __shared__ int idxI[RPB], idxJ[RPB], idxU[RPB];
    if (t < RPB)          idxI[t] = (base + t < Bn) ? ii[base + t] : -1;
    else if (t < 2 * RPB) { const int r = t - RPB;     idxJ[r] = (base + r < Bn) ? jj[base + r] : -1; }
    else if (t < 3 * RPB) { const int r = t - 2 * RPB; idxU[r] = (base + r < Bn) ? uu[base + r] : -1; }
    __syncthreads();

    // ---- issue U-row gathers FIRST; results consumed only after grid.sync ----
    float4 Ur[RPB / 16];
    #pragma unroll
    for (int k = 0; k < RPB / 16; ++k) {
        const int bu = idxU[rg + k * 16];
        Ur[k] = (bu >= 0) ? ((const float4*)(embed_user + (size_t)bu * F))[q]
                          : make_float4(0.f, 0.f, 0.f, 0.f);
    }

    // ---- phase A: gather I/J rows, accumulate block partials ----
    float4 aI = make_float4(0.f, 0.f, 0.f, 0.f);
    float4 aJ = make_float4(0.f, 0.f, 0.f, 0.f);
    float sqI = 0.f, sqJ = 0.f;
    #pragma unroll
    for (int k = 0; k < RPB / 16; ++k) {
        const int r  = rg + k * 16;
        const int bi = idxI[r];
        const int bj = idxJ[r];
        if (bi >= 0) {
            const float4 vi = ((const float4*)(embed_item + (size_t)bi * F))[q];
            aI.x += vi.x; aI.y += vi.y; aI.z += vi.z; aI.w += vi.w;
            sqI += vi.x*vi.x + vi.y*vi.y + vi.z*vi.z + vi.w*vi.w;
        }
        if (bj >= 0) {
            const float4 vj = ((const float4*)(embed_item + (size_t)bj * F))[q];
            aJ.x += vj.x; aJ.y += vj.y; aJ.z += vj.z; aJ.w += vj.w;
            sqJ += vj.x*vj.x + vj.y*vj.y + vj.z*vj.z + vj.w*vj.w;
        }
    }

    // Block partial of sI/sJ via LDS atomics (16 contributors/address).
    __shared__ float sI[F], sJ[F];
    if (t < F) { sI[t] = 0.f; sJ[t] = 0.f; }
    __syncthreads();
    atomicAdd(&sI[q*4+0], aI.x);
    atomicAdd(&sI[q*4+1], aI.y);
    atomicAdd(&sI[q*4+2], aI.z);
    atomicAdd(&sI[q*4+3], aI.w);
    atomicAdd(&sJ[q*4+0], aJ.x);
    atomicAdd(&sJ[q*4+1], aJ.y);
    atomicAdd(&sJ[q*4+2], aJ.z);
    atomicAdd(&sJ[q*4+3], aJ.w);

    for (int o = 32; o > 0; o >>= 1) {
        sqI += __shfl_down(sqI, o);
        sqJ += __shfl_down(sqJ, o);
    }
    __shared__ float wI[4], wJ[4];
    if (lane == 0) { wI[wave] = sqI; wJ[wave] = sqJ; }
    __syncthreads();

    if (t < 2 * F)
        wsA[(size_t)t * G + blockIdx.x] = (t < F) ? sI[t] : sJ[t - F];
    if (t == 0) {
        wsB[blockIdx.x]     = wI[0] + wI[1] + wI[2] + wI[3];
        wsB[G + blockIdx.x] = wJ[0] + wJ[1] + wJ[2] + wJ[3];
    }

    __threadfence();
    grid.sync();

    // ---- phase B: global sI/sJ from L2, dots from registered U rows ----
    __shared__ float sIJ[2 * F];
    if (t < 2 * F) {
        const float* row = wsA + (size_t)t * G;
        float4 a4 = make_float4(0.f, 0.f, 0.f, 0.f);
        int p = 0;
        for (; p + 4 <= G; p += 4) {
            const float4 v = *(const float4*)(row + p);
            a4.x += v.x; a4.y += v.y; a4.z += v.z; a4.w += v.w;
        }
        float a = a4.x + a4.y + a4.z + a4.w;
        for (; p < G; ++p) a += row[p];
        sIJ[t] = a;
    }
    __syncthreads();

    const float4 sIq = ((const float4*)sIJ)[q];
    const float4 sJq = ((const float4*)(sIJ + F))[q];

    float accLog = 0.f, accU2 = 0.f;
    #pragma unroll
    for (int k = 0; k < RPB / 16; ++k) {
        const int r  = rg + k * 16;
        const int bu = idxU[r];
        if (bu >= 0) {
            const float4 Uq = Ur[k];
            float pi = Uq.x*sIq.x + Uq.y*sIq.y + Uq.z*sIq.z + Uq.w*sIq.w;
            float pj = Uq.x*sJq.x + Uq.y*sJq.y + Uq.z*sJq.z + Uq.w*sJq.w;
            float u2 = Uq.x*Uq.x + Uq.y*Uq.y + Uq.z*Uq.z + Uq.w*Uq.w;
            for (int o = 1; o < 16; o <<= 1) {
                pi += __shfl_xor(pi, o);
                pj += __shfl_xor(pj, o);
                u2 += __shfl_xor(u2, o);
            }
            if (q == 0) {
                const int b = base + r;
                out[b]      = pi;
                out[Bn + b] = pj;
                const float x  = pi - pj;
                // stable log_sigmoid(x) = min(x,0) - log1p(exp(-|x|))
                const float ls = fminf(x, 0.f) - log1pf(__expf(-fabsf(x)));
                accLog += ls;
                accU2  += u2;
            }
        }
    }
    for (int o = 32; o > 0; o >>= 1) {
        accLog += __shfl_down(accLog, o);
        accU2  += __shfl_down(accU2, o);
    }
    __shared__ float wL[4], wU[4];
    if (lane == 0) { wL[wave] = accLog; wU[wave] = accU2; }
    __syncthreads();
    if (t == 0) {
        wsC[blockIdx.x]     = wU[0] + wU[1] + wU[2] + wU[3];
        wsC[G + blockIdx.x] = wL[0] + wL[1] + wL[2] + wL[3];
    }

    __threadfence();
    grid.sync();

    // ---- finalize: block 0 reduces per-block scalars ----
    if (blockIdx.x == 0) {
        float sq = 0.f, u2 = 0.f, lg = 0.f;
        for (int p = t; p < 2 * G; p += 256) sq += wsB[p];
        for (int p = t; p < G; p += 256) { u2 += wsC[p]; lg += wsC[G + p]; }
        for (int o = 32; o > 0; o >>= 1) {
            sq += __shfl_down(sq, o);
            u2 += __shfl_down(u2, o);
            lg += __shfl_down(lg, o);
        }
        __shared__ float fS[4], fU[4], fL[4];
        if (lane == 0) { fS[wave] = sq; fU[wave] = u2; fL[wave] = lg; }
        __syncthreads();
        if (t == 0) {
            const float reg = REG_C * (fS[0]+fS[1]+fS[2]+fS[3] + fU[0]+fU[1]+fU[2]+fU[3]);
            out[2 * Bn] = reg - (fL[0]+fL[1]+fL[2]+fL[3]) * INV_LN2;
        }
    }
}

// ---------------- non-cooperative fallback (3 kernels) ----------------

template<int RPB>
__global__ __launch_bounds__(256) void k_sum_items(
    const float* __restrict__ embed_item,
    const int* __restrict__ ii, const int* __restrict__ jj,
    float* __restrict__ wsA, float* __restrict__ wsB, int Bn, int G1)
{
    const int t = threadIdx.x, q = t & 15, rg = t >> 4;
    const int base = blockIdx.x * RPB;
    __shared__ int idx[2 * RPB];
    if (t < RPB)          idx[t] = (base + t < Bn) ? ii[base + t] : -1;
    else if (t < 2 * RPB) idx[t] = (base + (t - RPB) < Bn) ? jj[base + (t - RPB)] : -1;
    __syncthreads();
    float4 aI = make_float4(0,0,0,0), aJ = make_float4(0,0,0,0);
    float sqI = 0.f, sqJ = 0.f;
    #pragma unroll
    for (int k = 0; k < RPB / 16; ++k) {
        const int r = rg + k * 16;
        const int bi = idx[r], bj = idx[RPB + r];
        if (bi >= 0) {
            const float4 vi = ((const float4*)(embed_item + (size_t)bi * F))[q];
            aI.x += vi.x; aI.y += vi.y; aI.z += vi.z; aI.w += vi.w;
            sqI += vi.x*vi.x + vi.y*vi.y + vi.z*vi.z + vi.w*vi.w;
        }
        if (bj >= 0) {
            const float4 vj = ((const float4*)(embed_item + (size_t)bj * F))[q];
            aJ.x += vj.x; aJ.y += vj.y; aJ.z += vj.z; aJ.w += vj.w;
            sqJ += vj.x*vj.x + vj.y*vj.y + vj.z*vj.z + vj.w*vj.w;
        }
    }
    __shared__ float sI[F], sJ[F];
    if (t < F) { sI[t] = 0.f; sJ[t] = 0.f; }
    __syncthreads();
    atomicAdd(&sI[q*4+0], aI.x); atomicAdd(&sI[q*4+1], aI.y);
    atomicAdd(&sI[q*4+2], aI.z); atomicAdd(&sI[q*4+3], aI.w);
    atomicAdd(&sJ[q*4+0], aJ.x); atomicAdd(&sJ[q*4+1], aJ.y);
    atomicAdd(&sJ[q*4+2], aJ.z); atomicAdd(&sJ[q*4+3], aJ.w);
    for (int o = 32; o > 0; o >>= 1) { sqI += __shfl_down(sqI, o); sqJ += __shfl_down(sqJ, o); }
    __shared__ float wI[4], wJ[4];
    const int wave = t >> 6, lane = t & 63;
    if (lane == 0) { wI[wave] = sqI; wJ[wave] = sqJ; }
    __syncthreads();
    if (t < 2 * F) wsA[(size_t)t * G1 + blockIdx.x] = (t < F) ? sI[t] : sJ[t - F];
    if (t == 0) {
        wsB[blockIdx.x]      = wI[0]+wI[1]+wI[2]+wI[3];
        wsB[G1 + blockIdx.x] = wJ[0]+wJ[1]+wJ[2]+wJ[3];
    }
}

template<int RPB>
__global__ __launch_bounds__(256) void k_dots(
    const float* __restrict__ embed_user, const int* __restrict__ uu,
    const float* __restrict__ wsA, float* __restrict__ wsC,
    float* __restrict__ out, int Bn, int G1)
{
    const int t = threadIdx.x;
    const int base = blockIdx.x * RPB;
    __shared__ float sIJ[2 * F];
    __shared__ int idx[RPB];
    if (t < RPB) idx[t] = (base + t < Bn) ? uu[base + t] : -1;
    if (t < 2 * F) {
        const float* row = wsA + (size_t)t * G1;
        float4 a4 = make_float4(0,0,0,0);
        int p = 0;
        for (; p + 4 <= G1; p += 4) {
            const float4 v = *(const float4*)(row + p);
            a4.x += v.x; a4.y += v.y; a4.z += v.z; a4.w += v.w;
        }
        float a = a4.x + a4.y + a4.z + a4.w;
        for (; p < G1; ++p) a += row[p];
        sIJ[t] = a;
    }
    __syncthreads();
    const int q = t & 15, rg = t >> 4;
    const float4 sIq = ((const float4*)sIJ)[q];
    const float4 sJq = ((const float4*)(sIJ + F))[q];
    float accLog = 0.f, accU2 = 0.f;
    #pragma unroll
    for (int k = 0; k < RPB / 16; ++k) {
        const int r = rg + k * 16;
        const int bu = idx[r];
        if (bu >= 0) {
            const float4 Uq = ((const float4*)(embed_user + (size_t)bu * F))[q];
            float pi = Uq.x*sIq.x + Uq.y*sIq.y + Uq.z*sIq.z + Uq.w*sIq.w;
            float pj = Uq.x*sJq.x + Uq.y*sJq.y + Uq.z*sJq.z + Uq.w*sJq.w;
            float u2 = Uq.x*Uq.x + Uq.y*Uq.y + Uq.z*Uq.z + Uq.w*Uq.w;
            for (int o = 1; o < 16; o <<= 1) {
                pi += __shfl_xor(pi, o); pj += __shfl_xor(pj, o); u2 += __shfl_xor(u2, o);
            }
            if (q == 0) {
                const int b = base + r;
                out[b] = pi; out[Bn + b] = pj;
                const float x = pi - pj;
                accLog += fminf(x, 0.f) - log1pf(__expf(-fabsf(x)));
                accU2  += u2;
            }
        }
    }
    for (int o = 32; o > 0; o >>= 1) { accLog += __shfl_down(accLog, o); accU2 += __shfl_down(accU2, o); }
    __shared__ float wL[4], wU[4];
    const int wave = t >> 6, lane = t & 63;
    if (lane == 0) { wL[wave] = accLog; wU[wave] = accU2; }
    __syncthreads();
    if (t == 0) {
        const int G2 = gridDim.x;
        wsC[blockIdx.x]      = wU[0]+wU[1]+wU[2]+wU[3];
        wsC[G2 + blockIdx.x] = wL[0]+wL[1]+wL[2]+wL[3];
    }
}

__global__ __launch_bounds__(256) void k_finalize(
    const float* __restrict__ wsB, const float* __restrict__ wsC,
    float* __restrict__ out, int Bn, int G1, int G2)
{
    const int t = threadIdx.x;
    float sq = 0.f, u2 = 0.f, lg = 0.f;
    for (int p = t; p < 2 * G1; p += 256) sq += wsB[p];
    for (int p = t; p < G2; p += 256) { u2 += wsC[p]; lg += wsC[G2 + p]; }
    for (int o = 32; o > 0; o >>= 1) {
        sq += __shfl_down(sq, o); u2 += __shfl_down(u2, o); lg += __shfl_down(lg, o);
    }
    __shared__ float wS[4], wU[4], wL[4];
    const int wave = t >> 6, lane = t & 63;
    if (lane == 0) { wS[wave] = sq; wU[wave] = u2; wL[wave] = lg; }
    __syncthreads();
    if (t == 0) {
        const float reg = REG_C * (wS[0]+wS[1]+wS[2]+wS[3] + wU[0]+wU[1]+wU[2]+wU[3]);
        out[2 * Bn] = reg - (wL[0]+wL[1]+wL[2]+wL[3]) * INV_LN2;
    }
}

extern "C" void kernel_launch(void* const* d_in, const int* in_sizes, int n_in,
                              void* d_out, int out_size, void* d_ws, size_t ws_size,
                              hipStream_t stream) {
    const float* eu = (const float*)d_in[0];
    const float* ei = (const float*)d_in[1];
    const int*   u  = (const int*)d_in[2];
    const int*   ii = (const int*)d_in[3];
    const int*   jj = (const int*)d_in[4];
    float* out = (float*)d_out;
    float* ws  = (float*)d_ws;
    const int Bn = in_sizes[2];

    constexpr int RPB = 64;
    const int G = (Bn + RPB - 1) / RPB;      // 256 @ B=16384 -> 1 block/CU
    float* wsA = ws;                          // 2F * G floats
    float* wsB = wsA + (size_t)2 * F * G;     // 2G
    float* wsC = wsB + (size_t)2 * G;         // 2G

    if (G <= 1024) {                          // co-residency plausible
        void* args[] = { (void*)&eu, (void*)&ei, (void*)&u, (void*)&ii, (void*)&jj,
                         (void*)&wsA, (void*)&wsB, (void*)&wsC, (void*)&out, (void*)&Bn };
        hipError_t e = hipLaunchCooperativeKernel(
            reinterpret_cast<const void*>(&k_fused<RPB>),
            dim3(G), dim3(256), args, 0, stream);
        if (e == hipSuccess) return;
    }
    // fallback: non-cooperative 3-kernel path
    k_sum_items<RPB><<<G, 256, 0, stream>>>(ei, ii, jj, wsA, wsB, Bn, G);
    k_dots<RPB><<<G, 256, 0, stream>>>(eu, u, wsA, wsC, out, Bn, G);
    k_finalize<<<1, 256, 0, stream>>>(wsB, wsC, out, Bn, G, G);
}

// Round 10
// 406.558 us; speedup vs baseline: 1.2482x; 1.2482x over previous
//
#include <hip/hip_runtime.h>
#include <math.h>

#define F 64
#define REG_C 0.01f
#define INV_LN2 1.4426950408889634f

// ws float layout (no zero-init required; counter zeroed by k_sum_items):
//   wsA: [2F][G]  transposed stage-1 partials: wsA[f*G + p] = block p's
//                 partial of element f (rows 0..63 = sI, 64..127 = sJ).
//                 Transposed so stage-2's cross-block reduce is per-thread
//                 CONTIGUOUS float4 reads.
//   wsB: [2G]     per-block scalars: [p]=sum I^2, [G+p]=sum J^2
//   wsC: [2G]     per-block scalars: [p]=sum U^2, [G+p]=sum log_sigmoid
//   cnt: 1 int    arrival counter for the last-block finalize

template<int RPB>
__global__ __launch_bounds__(256) void k_sum_items(
    const float* __restrict__ embed_item,
    const int* __restrict__ ii,
    const int* __restrict__ jj,
    float* __restrict__ wsA,
    float* __restrict__ wsB,
    int* __restrict__ cnt,
    int Bn, int G)
{
    const int t  = threadIdx.x;
    const int q  = t & 15;   // float4 quad within the 64-float row
    const int rg = t >> 4;   // row group 0..15
    const int base = blockIdx.x * RPB;
    constexpr int K = RPB / 16;   // rows per thread (4 at RPB=64)

    // Zero the arrival counter for k_dots_fin (kernel-boundary ordering makes
    // this visible to every k_dots_fin block; graph replay re-zeroes it).
    if (blockIdx.x == 0 && t == 0) *cnt = 0;

    // Stage indices in LDS: coalesced load, removes dependent index loads
    // from the gather chain.
    __shared__ int idx[2 * RPB];
    if (t < RPB)          idx[t] = (base + t < Bn) ? ii[base + t] : -1;
    else if (t < 2 * RPB) idx[t] = (base + (t - RPB) < Bn) ? jj[base + (t - RPB)] : -1;
    __syncthreads();

    // Phase 1: ISSUE all 2K gathers back-to-back (maximum loads in flight;
    // no FP accumulate interleaved that could force early s_waitcnt).
    float4 vI[K], vJ[K];
    #pragma unroll
    for (int k = 0; k < K; ++k) {
        const int r  = rg + k * 16;
        const int bi = idx[r];
        const int bj = idx[RPB + r];
        vI[k] = (bi >= 0) ? ((const float4*)(embed_item + (size_t)bi * F))[q]
                          : make_float4(0.f, 0.f, 0.f, 0.f);
        vJ[k] = (bj >= 0) ? ((const float4*)(embed_item + (size_t)bj * F))[q]
                          : make_float4(0.f, 0.f, 0.f, 0.f);
    }

    // Phase 2: accumulate.
    float4 aI = make_float4(0.f, 0.f, 0.f, 0.f);
    float4 aJ = make_float4(0.f, 0.f, 0.f, 0.f);
    float sqI = 0.f, sqJ = 0.f;
    #pragma unroll
    for (int k = 0; k < K; ++k) {
        aI.x += vI[k].x; aI.y += vI[k].y; aI.z += vI[k].z; aI.w += vI[k].w;
        sqI += vI[k].x*vI[k].x + vI[k].y*vI[k].y + vI[k].z*vI[k].z + vI[k].w*vI[k].w;
        aJ.x += vJ[k].x; aJ.y += vJ[k].y; aJ.z += vJ[k].z; aJ.w += vJ[k].w;
        sqJ += vJ[k].x*vJ[k].x + vJ[k].y*vJ[k].y + vJ[k].z*vJ[k].z + vJ[k].w*vJ[k].w;
    }

    // Block partial of sI/sJ via LDS atomics (16 contributors/address).
    __shared__ float sI[F], sJ[F];
    if (t < F) { sI[t] = 0.f; sJ[t] = 0.f; }
    __syncthreads();
    atomicAdd(&sI[q*4+0], aI.x);
    atomicAdd(&sI[q*4+1], aI.y);
    atomicAdd(&sI[q*4+2], aI.z);
    atomicAdd(&sI[q*4+3], aI.w);
    atomicAdd(&sJ[q*4+0], aJ.x);
    atomicAdd(&sJ[q*4+1], aJ.y);
    atomicAdd(&sJ[q*4+2], aJ.z);
    atomicAdd(&sJ[q*4+3], aJ.w);

    for (int o = 32; o > 0; o >>= 1) {
        sqI += __shfl_down(sqI, o);
        sqJ += __shfl_down(sqJ, o);
    }
    __shared__ float wI[4], wJ[4];
    const int wave = t >> 6, lane = t & 63;
    if (lane == 0) { wI[wave] = sqI; wJ[wave] = sqJ; }
    __syncthreads();

    // Transposed write: element f of block p lands at wsA[f*G + p].
    if (t < 2 * F)
        wsA[(size_t)t * G + blockIdx.x] = (t < F) ? sI[t] : sJ[t - F];
    if (t == 0) {
        wsB[blockIdx.x]     = wI[0] + wI[1] + wI[2] + wI[3];
        wsB[G + blockIdx.x] = wJ[0] + wJ[1] + wJ[2] + wJ[3];
    }
}

template<int RPB>
__global__ __launch_bounds__(256) void k_dots_fin(
    const float* __restrict__ embed_user,
    const int* __restrict__ uu,
    const float* __restrict__ wsA,
    const float* __restrict__ wsB,
    float* __restrict__ wsC,
    int* __restrict__ cnt,
    float* __restrict__ out,
    int Bn, int G)
{
    const int t  = threadIdx.x;
    const int q  = t & 15;
    const int rg = t >> 4;
    const int wave = t >> 6, lane = t & 63;
    const int base = blockIdx.x * RPB;
    constexpr int K = RPB / 16;

    __shared__ int idxU[RPB];
    if (t < RPB) idxU[t] = (base + t < Bn) ? uu[base + t] : -1;
    __syncthreads();

    // Issue ALL U-row gathers first; consumed only after the wsA reduce, so
    // HBM latency hides under the L2-resident reduce below.
    float4 Ur[K];
    #pragma unroll
    for (int k = 0; k < K; ++k) {
        const int bu = idxU[rg + k * 16];
        Ur[k] = (bu >= 0) ? ((const float4*)(embed_user + (size_t)bu * F))[q]
                          : make_float4(0.f, 0.f, 0.f, 0.f);
    }

    // Cross-block reduce of stage-1 partials: thread t (<128) sums its
    // CONTIGUOUS row wsA[t*G .. t*G+G) with independent float4 reads (L2-hit).
    __shared__ float sIJ[2 * F];
    if (t < 2 * F) {
        const float* row = wsA + (size_t)t * G;
        float4 a4 = make_float4(0.f, 0.f, 0.f, 0.f);
        int p = 0;
        for (; p + 4 <= G; p += 4) {
            const float4 v = *(const float4*)(row + p);
            a4.x += v.x; a4.y += v.y; a4.z += v.z; a4.w += v.w;
        }
        float a = a4.x + a4.y + a4.z + a4.w;
        for (; p < G; ++p) a += row[p];
        sIJ[t] = a;
    }
    __syncthreads();

    const float4 sIq = ((const float4*)sIJ)[q];
    const float4 sJq = ((const float4*)(sIJ + F))[q];

    float accLog = 0.f, accU2 = 0.f;
    #pragma unroll
    for (int k = 0; k < K; ++k) {
        const int r = rg + k * 16;
        if (idxU[r] >= 0) {
            const float4 Uq = Ur[k];
            float pi = Uq.x*sIq.x + Uq.y*sIq.y + Uq.z*sIq.z + Uq.w*sIq.w;
            float pj = Uq.x*sJq.x + Uq.y*sJq.y + Uq.z*sJq.z + Uq.w*sJq.w;
            float u2 = Uq.x*Uq.x + Uq.y*Uq.y + Uq.z*Uq.z + Uq.w*Uq.w;
            for (int o = 1; o < 16; o <<= 1) {
                pi += __shfl_xor(pi, o);
                pj += __shfl_xor(pj, o);
                u2 += __shfl_xor(u2, o);
            }
            if (q == 0) {
                const int b = base + r;
                out[b]      = pi;
                out[Bn + b] = pj;
                const float x = pi - pj;
                // stable log_sigmoid(x) = min(x,0) - log1p(exp(-|x|))
                accLog += fminf(x, 0.f) - log1pf(__expf(-fabsf(x)));
                accU2  += u2;
            }
        }
    }
    for (int o = 32; o > 0; o >>= 1) {
        accLog += __shfl_down(accLog, o);
        accU2  += __shfl_down(accU2, o);
    }
    __shared__ float wL[4], wU[4];
    if (lane == 0) { wL[wave] = accLog; wU[wave] = accU2; }
    __syncthreads();

    // Publish this block's scalars, then last-arriving block finalizes
    // (threadfence-reduction pattern; device-scope fence + atomic handles
    // cross-XCD visibility per Guidelines 12/16). The `% G` makes the
    // trigger idempotent if a profiler replay re-runs this kernel without
    // re-running k_sum_items (cnt not re-zeroed).
    __shared__ int isLast;
    if (t == 0) {
        wsC[blockIdx.x]     = wU[0] + wU[1] + wU[2] + wU[3];
        wsC[G + blockIdx.x] = wL[0] + wL[1] + wL[2] + wL[3];
        __threadfence();                       // release wsC writes
        const int prev = atomicAdd(cnt, 1);    // device-scope
        isLast = ((prev % G) == G - 1);
    }
    __syncthreads();

    if (isLast) {
        __threadfence();                       // acquire others' wsC writes
        float sq = 0.f, u2 = 0.f, lg = 0.f;
        for (int p = t; p < 2 * G; p += 256) sq += wsB[p];
        for (int p = t; p < G; p += 256) { u2 += wsC[p]; lg += wsC[G + p]; }
        for (int o = 32; o > 0; o >>= 1) {
            sq += __shfl_down(sq, o);
            u2 += __shfl_down(u2, o);
            lg += __shfl_down(lg, o);
        }
        __shared__ float fS[4], fU[4], fL[4];
        if (lane == 0) { fS[wave] = sq; fU[wave] = u2; fL[wave] = lg; }
        __syncthreads();
        if (t == 0) {
            const float reg = REG_C * (fS[0]+fS[1]+fS[2]+fS[3] +
                                       fU[0]+fU[1]+fU[2]+fU[3]);
            out[2 * Bn] = reg - (fL[0]+fL[1]+fL[2]+fL[3]) * INV_LN2;
        }
    }
}

extern "C" void kernel_launch(void* const* d_in, const int* in_sizes, int n_in,
                              void* d_out, int out_size, void* d_ws, size_t ws_size,
                              hipStream_t stream) {
    const float* eu = (const float*)d_in[0];
    const float* ei = (const float*)d_in[1];
    const int*   u  = (const int*)d_in[2];
    const int*   ii = (const int*)d_in[3];
    const int*   jj = (const int*)d_in[4];
    float* out = (float*)d_out;
    float* ws  = (float*)d_ws;
    const int Bn = in_sizes[2];

    constexpr int RPB = 64;
    const int G = (Bn + RPB - 1) / RPB;       // 256 blocks @ B=16384 -> all CUs

    float* wsA = ws;                           // 2F * G floats
    float* wsB = wsA + (size_t)2 * F * G;      // 2G
    float* wsC = wsB + (size_t)2 * G;          // 2G
    int*   cnt = (int*)(wsC + (size_t)2 * G);  // 1 int

    k_sum_items<RPB><<<G, 256, 0, stream>>>(ei, ii, jj, wsA, wsB, cnt, Bn, G);
    k_dots_fin<RPB><<<G, 256, 0, stream>>>(eu, u, wsA, wsB, wsC, cnt, out, Bn, G);
}